// Round 5
// baseline (199.824 us; speedup 1.0000x reference)
//
#include <hip/hip_runtime.h>

typedef _Float16 f16;
typedef __attribute__((ext_vector_type(4))) _Float16 f16x4;
typedef __attribute__((ext_vector_type(8))) _Float16 f16x8;
typedef __attribute__((ext_vector_type(4))) float f32x4;

#define MM 2048
#define DD 256
#define LOG2E 1.44269504088896340736f

__device__ __forceinline__ void gload_lds16(const void* g, void* l) {
    __builtin_amdgcn_global_load_lds(
        (const __attribute__((address_space(1))) unsigned int*)g,
        (__attribute__((address_space(3))) unsigned int*)l, 16, 0, 0);
}
__device__ __forceinline__ f32x4 mfma16(f16x8 a, f16x8 b, f32x4 c) {
    return __builtin_amdgcn_mfma_f32_16x16x32_f16(a, b, c, 0, 0, 0);
}

// Prep (verified R1/R2): memory f32 [2048][256] -> two fp16 copies, 16B-unit layouts.
// Kprep: per 32-row tile b: unit(u,kk) = memory[32b+kk][8u..8u+7]   (u=0..31, kk=0..31)
// VTprep: per 32-row tile b: unit(u,d)  = memory[32b+8u+e][d] e=0..7 (u=0..3,  d=0..255)
__global__ void prep_kernel(const float* __restrict__ mem,
                            f16* __restrict__ kprep, f16* __restrict__ vtprep) {
    int t = blockIdx.x * blockDim.x + threadIdx.x;
    if (t < 65536) {
        int b = t >> 10, r = t & 1023, u = r >> 5, kk = r & 31;
        const float* src = mem + (b * 32 + kk) * DD + u * 8;
        f16 o8[8];
#pragma unroll
        for (int e = 0; e < 8; ++e) o8[e] = (f16)src[e];
        *(f16x8*)(kprep + (size_t)t * 8) = *(f16x8*)o8;
    } else {
        int t2 = t - 65536;
        int b = t2 >> 10, r = t2 & 1023, u = r >> 8, d = r & 255;
        f16 o8[8];
#pragma unroll
        for (int e = 0; e < 8; ++e) o8[e] = (f16)mem[(b * 32 + u * 8 + e) * DD + d];
        *(f16x8*)(vtprep + (size_t)t2 * 8) = *(f16x8*)o8;
    }
}

// 1024 blocks x 256 threads (4 waves, 16 q-rows each). KV tile = 32, 64 iters.
// Swapped QK^T (q lane-local), defer-max, ones-MFMA row-sum.
// K double-buffered (prefetch 1 tile), VT single-buffered (stage hides under QK+SM).
// LDS = 32K (K) + 16K (VT) + 5K (P, row stride 40: 32 vals + 8 pad) -> 3 blocks/CU.
__launch_bounds__(256, 3)
__global__ void attn_kernel(const float* __restrict__ q,
                            const f16* __restrict__ kprep,
                            const f16* __restrict__ vtprep,
                            float* __restrict__ out) {
    __shared__ __align__(16) f16 klds[2][8192];   // 32KB K tiles, unit [u=32][kk=32]
    __shared__ __align__(16) f16 vtlds[8192];     // 16KB VT tile, unit [u=4][d=256]
    __shared__ __align__(16) f16 plds[4][16 * 40];  // per-wave P, row stride 40 f16

    const int tid = threadIdx.x;
    const int w = __builtin_amdgcn_readfirstlane(tid >> 6);
    const int lane = tid & 63;
    const int g = lane >> 4;
    const int l15 = lane & 15;
    const int q0 = blockIdx.x * 64 + w * 16;

    // Q A-frags: qf[dc] lane(g,l15) elem j = Q[q0+l15][32dc+8g+j]
    f16x8 qf[8];
#pragma unroll
    for (int dc = 0; dc < 8; ++dc) {
        const float* src = q + (size_t)(q0 + l15) * DD + dc * 32 + g * 8;
        float4 a = *(const float4*)src;
        float4 b2 = *(const float4*)(src + 4);
        f16 t8[8] = {(f16)a.x, (f16)a.y, (f16)a.z, (f16)a.w,
                     (f16)b2.x, (f16)b2.y, (f16)b2.z, (f16)b2.w};
        qf[dc] = *(f16x8*)t8;
    }

    f32x4 o[16];
#pragma unroll
    for (int dt = 0; dt < 16; ++dt) o[dt] = (f32x4){0.f, 0.f, 0.f, 0.f};
    f32x4 lsum = (f32x4){0.f, 0.f, 0.f, 0.f};
    float mrun = -1e30f;

    f16x8 ones;
#pragma unroll
    for (int e = 0; e < 8; ++e) ones[e] = (f16)1.0f;

    f16* pw = plds[w];

#define STAGE_K(b_, c_)                                                   \
    do {                                                                  \
        const f16* s_ = kprep + (size_t)(b_)*8192;                        \
        _Pragma("unroll")                                                 \
        for (int i_ = 0; i_ < 4; ++i_)                                    \
            gload_lds16(s_ + i_ * 2048 + tid * 8,                         \
                        &klds[c_][i_ * 2048 + w * 512]);                  \
    } while (0)
#define STAGE_VT(b_)                                                      \
    do {                                                                  \
        const f16* s_ = vtprep + (size_t)(b_)*8192;                       \
        _Pragma("unroll")                                                 \
        for (int i_ = 0; i_ < 4; ++i_)                                    \
            gload_lds16(s_ + i_ * 2048 + tid * 8,                         \
                        &vtlds[i_ * 2048 + w * 512]);                     \
    } while (0)

    STAGE_K(0, 0);

    for (int b = 0; b < 64; ++b) {
        const int c = b & 1;
        // Barrier 1: K[c] staged+drained; previous PV done reading vtlds.
        __syncthreads();
        STAGE_VT(b);
        if (b < 63) STAGE_K(b + 1, c ^ 1);

        // ---- S^T = K Q^T: s0[rr]=S[k=4g+rr][q=l15], s1[rr]=S[k=16+4g+rr][q=l15]
        f32x4 s0 = (f32x4){0.f, 0.f, 0.f, 0.f};
        f32x4 s1 = (f32x4){0.f, 0.f, 0.f, 0.f};
        __builtin_amdgcn_s_setprio(1);
#pragma unroll
        for (int dc = 0; dc < 8; ++dc) {
            f16x8 bk0 = *(const f16x8*)(&klds[c][((dc * 4 + g) * 32 + l15) * 8]);
            f16x8 bk1 = *(const f16x8*)(&klds[c][((dc * 4 + g) * 32 + 16 + l15) * 8]);
            s0 = mfma16(bk0, qf[dc], s0);
            s1 = mfma16(bk1, qf[dc], s1);
        }
        __builtin_amdgcn_s_setprio(0);

        // ---- online softmax (base-2), defer-max: cross-lane ops only on trigger
        float a0 = fmaxf(fmaxf(s0[0], s0[1]), fmaxf(s0[2], s0[3]));
        float a1 = fmaxf(fmaxf(s1[0], s1[1]), fmaxf(s1[2], s1[3]));
        float sm = fmaxf(a0, a1) * LOG2E;
        if (__any(sm > mrun + 8.0f)) {
            sm = fmaxf(sm, __shfl_xor(sm, 16));
            sm = fmaxf(sm, __shfl_xor(sm, 32));
            const float mnew = fmaxf(mrun, sm);
            const float fct = __builtin_amdgcn_exp2f(mrun - mnew);
            mrun = mnew;
            // fct indexed by q=l15; O/lsum rows are q=4g+rr -> width-16 shfl
            const float f0 = __shfl(fct, 4 * g + 0, 16);
            const float f1 = __shfl(fct, 4 * g + 1, 16);
            const float f2 = __shfl(fct, 4 * g + 2, 16);
            const float f3 = __shfl(fct, 4 * g + 3, 16);
#pragma unroll
            for (int dt = 0; dt < 16; ++dt) {
                o[dt][0] *= f0; o[dt][1] *= f1;
                o[dt][2] *= f2; o[dt][3] *= f3;
            }
            lsum[0] *= f0; lsum[1] *= f1; lsum[2] *= f2; lsum[3] *= f3;
        }
        float pr[8];
#pragma unroll
        for (int rr = 0; rr < 4; ++rr) {
            pr[rr] = __builtin_amdgcn_exp2f(__builtin_fmaf(s0[rr], LOG2E, -mrun));
            pr[4 + rr] = __builtin_amdgcn_exp2f(__builtin_fmaf(s1[rr], LOG2E, -mrun));
        }
        // P[q=l15][16kt+4g+rr] -> per-wave LDS (row stride 40 f16)
        f16x4 p0 = {(f16)pr[0], (f16)pr[1], (f16)pr[2], (f16)pr[3]};
        f16x4 p1 = {(f16)pr[4], (f16)pr[5], (f16)pr[6], (f16)pr[7]};
        *(f16x4*)(pw + l15 * 40 + 4 * g) = p0;
        *(f16x4*)(pw + l15 * 40 + 16 + 4 * g) = p1;
        // A-frag: pa elem j = P[q=l15][k=8g+j]
        f16x8 pa = *(const f16x8*)(pw + l15 * 40 + g * 8);

        // Barrier 2: VT(b) staged+drained (K(b+1) also lands early; harmless).
        __syncthreads();

        // ---- O += P V  (B-frag: VT unit(g, 16dt+l15) = V[k=8g+j][16dt+l15])
        __builtin_amdgcn_s_setprio(1);
#pragma unroll
        for (int dt = 0; dt < 16; ++dt) {
            f16x8 bv = *(const f16x8*)(&vtlds[(g * 256 + dt * 16 + l15) * 8]);
            o[dt] = mfma16(pa, bv, o[dt]);
        }
        lsum = mfma16(pa, ones, lsum);  // row-sums, same C layout as O
        __builtin_amdgcn_s_setprio(0);
    }

    // ---- epilogue: O rows are q0+4g+rr; lsum[rr] is that row's denominator
    float inv0 = 1.0f / lsum[0], inv1 = 1.0f / lsum[1];
    float inv2 = 1.0f / lsum[2], inv3 = 1.0f / lsum[3];
#pragma unroll
    for (int dt = 0; dt < 16; ++dt) {
        const size_t base = (size_t)(q0 + 4 * g) * DD + dt * 16 + l15;
        out[base] = o[dt][0] * inv0;
        out[base + DD] = o[dt][1] * inv1;
        out[base + 2 * DD] = o[dt][2] * inv2;
        out[base + 3 * DD] = o[dt][3] * inv3;
    }
}

extern "C" void kernel_launch(void* const* d_in, const int* in_sizes, int n_in,
                              void* d_out, int out_size, void* d_ws, size_t ws_size,
                              hipStream_t stream) {
    const float* memory = (const float*)d_in[0];
    const float* query = (const float*)d_in[1];
    float* out = (float*)d_out;
    f16* kprep = (f16*)d_ws;                 // 1 MB
    f16* vtprep = kprep + (size_t)MM * DD;   // 1 MB
    prep_kernel<<<512, 256, 0, stream>>>(memory, kprep, vtprep);
    attn_kernel<<<1024, 256, 0, stream>>>(query, kprep, vtprep, out);
}